// Round 12
// baseline (477.764 us; speedup 1.0000x reference)
//
#include <hip/hip_runtime.h>
#include <hip/hip_bf16.h>

#define NROWS 262144
#define CDIM  128
#define BN_EPS 1e-5f
#define GGRID 1024
#define SPB   (NROWS / 16 / GGRID)   // 16 stripes (16 rows) per block

typedef __attribute__((ext_vector_type(8))) short bf16x8;
typedef __attribute__((ext_vector_type(4))) float f32x4;
#define LROW 136   // LDS row stride in shorts (128 data + 8 pad)

static __device__ __forceinline__ unsigned int f2bf_rtn(float f) {
  unsigned int u = __float_as_uint(f);
  return (u + 0x7fffu + ((u >> 16) & 1u)) >> 16;
}
static __device__ __forceinline__ float bf2f(unsigned int b) {
  return __uint_as_float(b << 16);
}

// h = in @ W^T + bias.  NORM: in' = relu(in*scale+shift) first (in-place safe).
// A staged via LDS (bf16 hi/lo planes, double-buffered) with 2-deep register
// prefetch (loads for stripe s+2 issued at iter s -> a full iteration of
// latency cover).  C stored via LDS transpose staging so every global store
// instruction writes full 128-B lines (fixes the WRITE_SIZE inflation measured
// in rounds 4-11: partial 64-B quarter-stores caused HBM read-modify-write).
template <bool NORM>
__global__ void __launch_bounds__(256, 4)
gemm_bn(const float* __restrict__ in, const float* __restrict__ W,
        const float* __restrict__ bias,
        const float* __restrict__ scsh_in,   // [256] scale|shift (NORM only)
        float* __restrict__ hout, float* __restrict__ part)
{
  __shared__ __align__(16) short lds[2][2][16][LROW];  // 17408 B
  __shared__ __align__(16) float cstg[16][CDIM];       //  8192 B

  const int tid  = threadIdx.x;
  const int lane = tid & 63;
  const int wave = tid >> 6;
  const int l15  = lane & 15;
  const int lq   = lane >> 4;
  const int wcol = wave * 32;
  const int srow = tid >> 4;         // staging row 0..15
  const int sk0  = (tid & 15) * 8;   // staging k-chunk

  // ---- B fragments in registers (hi/lo split) ----
  bf16x8 bh[2][4], bl[2][4];
#pragma unroll
  for (int jt = 0; jt < 2; ++jt) {
    const float* wrow = W + (wcol + jt * 16 + l15) * CDIM;
#pragma unroll
    for (int ks = 0; ks < 4; ++ks) {
      const int k0 = ks * 32 + lq * 8;
      f32x4 w0 = *(const f32x4*)(wrow + k0);
      f32x4 w1 = *(const f32x4*)(wrow + k0 + 4);
      float wv[8] = {w0.x,w0.y,w0.z,w0.w,w1.x,w1.y,w1.z,w1.w};
#pragma unroll
      for (int e = 0; e < 8; ++e) {
        unsigned int h = f2bf_rtn(wv[e]);
        bh[jt][ks][e] = (short)h;
        bl[jt][ks][e] = (short)f2bf_rtn(wv[e] - bf2f(h));
      }
    }
  }

  float scv[8], shv[8];
  if constexpr (NORM) {
#pragma unroll
    for (int e = 0; e < 8; ++e) {
      scv[e] = scsh_in[sk0 + e];
      shv[e] = scsh_in[CDIM + sk0 + e];
    }
  }

  const float bias0 = bias[wcol + l15];
  const float bias1 = bias[wcol + 16 + l15];
  float s0 = 0.f, s1 = 0.f, q0 = 0.f, q1 = 0.f;

  const int row0 = blockIdx.x * (SPB * 16);

  auto loadS = [&](int s, f32x4& g0, f32x4& g1) {
    const float* ap = in + (size_t)(row0 + s * 16 + srow) * CDIM + sk0;
    g0 = *(const f32x4*)ap;
    g1 = *(const f32x4*)(ap + 4);
  };

  auto cvt_write = [&](int buf, f32x4 g0, f32x4 g1) {
    float av[8] = {g0.x,g0.y,g0.z,g0.w,g1.x,g1.y,g1.z,g1.w};
    if constexpr (NORM) {
#pragma unroll
      for (int e = 0; e < 8; ++e)
        av[e] = fmaxf(av[e] * scv[e] + shv[e], 0.f);
    }
    bf16x8 hi, lo;
#pragma unroll
    for (int e = 0; e < 8; ++e) {
      unsigned int h = f2bf_rtn(av[e]);
      hi[e] = (short)h;
      lo[e] = (short)f2bf_rtn(av[e] - bf2f(h));
    }
    *(bf16x8*)&lds[buf][0][srow][sk0] = hi;
    *(bf16x8*)&lds[buf][1][srow][sk0] = lo;
  };

  // one iteration; gA = P-set to refill with stripe s+2, gB = P-set holding s+1
  auto body = [&](int s, f32x4& gA0, f32x4& gA1, f32x4& gB0, f32x4& gB1) {
    const int cur = s & 1;
    const int r0 = row0 + s * 16;

    if (s + 2 < SPB) loadS(s + 2, gA0, gA1);   // 2-deep prefetch

    f32x4 acc0 = {0.f,0.f,0.f,0.f};
    f32x4 acc1 = {0.f,0.f,0.f,0.f};
#pragma unroll
    for (int ks = 0; ks < 4; ++ks) {
      const int kc = ks * 32 + lq * 8;
      bf16x8 ah = *(const bf16x8*)&lds[cur][0][l15][kc];
      bf16x8 al = *(const bf16x8*)&lds[cur][1][l15][kc];
      acc0 = __builtin_amdgcn_mfma_f32_16x16x32_bf16(al, bh[0][ks], acc0, 0, 0, 0);
      acc0 = __builtin_amdgcn_mfma_f32_16x16x32_bf16(ah, bl[0][ks], acc0, 0, 0, 0);
      acc0 = __builtin_amdgcn_mfma_f32_16x16x32_bf16(ah, bh[0][ks], acc0, 0, 0, 0);
      acc1 = __builtin_amdgcn_mfma_f32_16x16x32_bf16(al, bh[1][ks], acc1, 0, 0, 0);
      acc1 = __builtin_amdgcn_mfma_f32_16x16x32_bf16(ah, bl[1][ks], acc1, 0, 0, 0);
      acc1 = __builtin_amdgcn_mfma_f32_16x16x32_bf16(ah, bh[1][ks], acc1, 0, 0, 0);
    }

    if (s + 1 < SPB) cvt_write(cur ^ 1, gB0, gB1);  // consumes loads from iter s-1
    __syncthreads();   // buf[cur^1] ready; all reads of buf[cur] done; cstg free

    // ---- C store: acc -> LDS transpose -> full-line global stores ----
#pragma unroll
    for (int r = 0; r < 4; ++r) {
      float h0 = acc0[r] + bias0;
      float h1 = acc1[r] + bias1;
      s0 += h0; q0 += h0 * h0;
      s1 += h1; q1 += h1 * h1;
      cstg[lq * 4 + r][wcol + l15]      = h0;
      cstg[lq * 4 + r][wcol + 16 + l15] = h1;
    }
    __syncthreads();
    const int srow2 = tid >> 5;    // 0..7
    const int schk  = tid & 31;    // f32x4 chunk within row
#pragma unroll
    for (int p = 0; p < 2; ++p) {
      f32x4 v = *(const f32x4*)&cstg[p * 8 + srow2][schk * 4];
      __builtin_nontemporal_store(
          v, (f32x4*)(hout + (size_t)(r0 + p * 8 + srow2) * CDIM + schk * 4));
    }
  };

  // prologue: stage stripe 0, prefetch stripe 1
  f32x4 pA0, pA1, pB0, pB1;
  loadS(0, pA0, pA1);
  cvt_write(0, pA0, pA1);
  loadS(1, pB0, pB1);
  __syncthreads();

  for (int s = 0; s < SPB; s += 2) {
    body(s,     pA0, pA1, pB0, pB1);
    body(s + 1, pB0, pB1, pA0, pA1);
  }

  // reduce quarters; store per-block partials (coalesced, no atomics)
  s0 += __shfl_xor(s0, 16); s0 += __shfl_xor(s0, 32);
  s1 += __shfl_xor(s1, 16); s1 += __shfl_xor(s1, 32);
  q0 += __shfl_xor(q0, 16); q0 += __shfl_xor(q0, 32);
  q1 += __shfl_xor(q1, 16); q1 += __shfl_xor(q1, 32);
  float* pb = part + (size_t)blockIdx.x * 256;
  if (lane < 16) {
    pb[wcol + lane]              = s0;
    pb[wcol + 16 + lane]         = s1;
    pb[CDIM + wcol + lane]       = q0;
    pb[CDIM + wcol + 16 + lane]  = q1;
  }
}

// Reduce per-block partials -> scale|shift per column. Grid = 128 (1 col/block).
__global__ void __launch_bounds__(256)
bn_stats(const float* __restrict__ part, const float* __restrict__ gamma,
         const float* __restrict__ beta, float* __restrict__ scsh)
{
  const int c = blockIdx.x;
  const int t = threadIdx.x;
  float s = 0.f, q = 0.f;
  for (int b = t; b < GGRID; b += 256) {
    s += part[(size_t)b * 256 + c];
    q += part[(size_t)b * 256 + CDIM + c];
  }
  __shared__ float rs[256], rq[256];
  rs[t] = s; rq[t] = q;
  __syncthreads();
#pragma unroll
  for (int off = 128; off >= 1; off >>= 1) {
    if (t < off) { rs[t] += rs[t + off]; rq[t] += rq[t + off]; }
    __syncthreads();
  }
  if (t == 0) {
    const float inv_n = 1.0f / (float)NROWS;
    float m  = rs[0] * inv_n;
    float v  = rq[0] * inv_n - m * m;
    float sc = gamma[c] * rsqrtf(v + BN_EPS);
    scsh[c]        = sc;
    scsh[CDIM + c] = beta[c] - m * sc;
  }
}

// out = relu(h2*sc+sh) + x. Lane-contiguous, 4 grid-stride streams/thread.
__global__ void __launch_bounds__(256)
finalize(const f32x4* __restrict__ h2, const f32x4* __restrict__ xin,
         const float* __restrict__ scsh, f32x4* __restrict__ outp)
{
  const int tid0 = blockIdx.x * blockDim.x + threadIdx.x;  // f32x4 index
  const int c0 = (tid0 * 4) & (CDIM - 1);                  // 4 consecutive cols

  float sc[4], sh[4];
#pragma unroll
  for (int e = 0; e < 4; ++e) {
    sc[e] = scsh[c0 + e];
    sh[e] = scsh[CDIM + c0 + e];
  }

  const int n4 = NROWS * CDIM / 4;
  const int GR = gridDim.x * blockDim.x;   // grid 4096: GR*4 % 128 == 0
  for (int base = tid0; base < n4; base += GR * 4) {
    f32x4 h[4], xv[4], o[4];
#pragma unroll
    for (int u = 0; u < 4; ++u) {
      h[u]  = __builtin_nontemporal_load(&h2[base + u * GR]);
      xv[u] = __builtin_nontemporal_load(&xin[base + u * GR]);
    }
#pragma unroll
    for (int u = 0; u < 4; ++u) {
      o[u].x = fmaxf(h[u].x * sc[0] + sh[0], 0.f) + xv[u].x;
      o[u].y = fmaxf(h[u].y * sc[1] + sh[1], 0.f) + xv[u].y;
      o[u].z = fmaxf(h[u].z * sc[2] + sh[2], 0.f) + xv[u].z;
      o[u].w = fmaxf(h[u].w * sc[3] + sh[3], 0.f) + xv[u].w;
    }
#pragma unroll
    for (int u = 0; u < 4; ++u)
      __builtin_nontemporal_store(o[u], &outp[base + u * GR]);
  }
}

extern "C" void kernel_launch(void* const* d_in, const int* in_sizes, int n_in,
                              void* d_out, int out_size, void* d_ws, size_t ws_size,
                              hipStream_t stream) {
  (void)in_sizes; (void)n_in; (void)out_size; (void)ws_size;
  const float* x   = (const float*)d_in[0];
  const float* W1  = (const float*)d_in[1];
  const float* b1  = (const float*)d_in[2];
  const float* g1  = (const float*)d_in[3];
  const float* be1 = (const float*)d_in[4];
  const float* W2  = (const float*)d_in[5];
  const float* b2  = (const float*)d_in[6];
  const float* g2  = (const float*)d_in[7];
  const float* be2 = (const float*)d_in[8];

  float* hbuf  = (float*)d_out;                 // h1 then h2, in place
  float* part1 = (float*)d_ws;                  // [GGRID][256]
  float* part2 = part1 + (size_t)GGRID * 256;   // [GGRID][256]
  float* scsh1 = part2 + (size_t)GGRID * 256;   // [256]
  float* scsh2 = scsh1 + 256;                   // [256]
  // all ws regions fully written before read -> no memset needed

  gemm_bn<false><<<GGRID, 256, 0, stream>>>(x, W1, b1, nullptr, hbuf, part1);
  bn_stats<<<CDIM, 256, 0, stream>>>(part1, g1, be1, scsh1);
  gemm_bn<true><<<GGRID, 256, 0, stream>>>(hbuf, W2, b2, scsh1, hbuf, part2);
  bn_stats<<<CDIM, 256, 0, stream>>>(part2, g2, be2, scsh2);
  finalize<<<4096, 256, 0, stream>>>((const f32x4*)hbuf, (const f32x4*)x,
                                     scsh2, (f32x4*)d_out);
}